// Round 1
// baseline (272.506 us; speedup 1.0000x reference)
//
#include <hip/hip_runtime.h>
#include <math.h>

#define TL 2048
#define KROW 4096
#define PI_D 3.14159265358979323846

// ---------------------------------------------------------------------------
// Build the 80 shift kernels (64 frame shifts + 16 event shifts).
// k[d] = -(sin(theta)/N)*(-1)^d * cot(pi*d/N - beta),  d in [-2047,2047]
// theta = 2*pi*m*s/M, beta = pi*s/M, N=6144, m=3072, M=3073, s=shift*2048/3
// alpha->0 limit gives 1.0 (covers shift==0 -> identity).
// ---------------------------------------------------------------------------
__global__ __launch_bounds__(256) void build_kernels_k(const float* __restrict__ shifts,
                                                       float* __restrict__ kerF,
                                                       float* __restrict__ kerE) {
  int b = blockIdx.x;
  float sf;
  float* row;
  if (b < 64) {
    float fj = (float)b * (1.0f / 63.0f);
    sf = fj * (2048.0f / 3.0f);
    row = kerF + b * KROW;
  } else {
    sf = shifts[b - 64] * (2048.0f / 3.0f);
    row = kerE + (b - 64) * KROW;
  }
  double s = (double)sf;
  double beta = PI_D * s / 3073.0;
  double y = 3072.0 * s / 3073.0;
  double r = y - rint(y);
  double w = -sin(2.0 * PI_D * r) / 6144.0;
  for (int idx = threadIdx.x; idx < 4095; idx += 256) {
    int d = idx - 2047;
    double x = PI_D * (double)d / 6144.0 - beta;
    float val;
    if (fabs(x) < 1e-9) {
      val = 1.0f;  // alpha -> 0 limit
    } else {
      double c = w * (cos(x) / sin(x));
      if (d & 1) c = -c;
      val = (float)c;
    }
    row[idx] = val;
  }
}

// ---------------------------------------------------------------------------
// Step a: t_shift[p,t] = sum_u time[p,u] * kerE[p][t-u+2047]
// ---------------------------------------------------------------------------
__global__ __launch_bounds__(256) void shift_time_k(const float* __restrict__ time_in,
                                                    const float* __restrict__ kerE,
                                                    float* __restrict__ tsh) {
  int p = blockIdx.x >> 3, tile = blockIdx.x & 7;
  __shared__ float a[TL];
  __shared__ float kw[2304];
  int t0 = tile * 256;
  const float* krow = kerE + p * KROW;
  for (int i = threadIdx.x; i < TL; i += 256) a[i] = time_in[p * TL + i];
  for (int i = threadIdx.x; i < 2303; i += 256) kw[i] = krow[t0 + i];
  __syncthreads();
  float acc = 0.f;
  int base = threadIdx.x + 2047;
#pragma unroll 8
  for (int u = 0; u < TL; ++u) acc = fmaf(a[u], kw[base - u], acc);
  tsh[p * TL + t0 + threadIdx.x] = acc;
}

// ---------------------------------------------------------------------------
// Step b (dominant): expT[p,j,t] = sum_u tsh[p,u] * kerF[j][t-u+2047]
// Block = (j, 256-t tile). Thread: p = tid&15 owns 16 consecutive t.
// Register sliding window: per 16-u chunk 31 window loads + 16 bcast + 256 FMA.
// ---------------------------------------------------------------------------
__global__ __launch_bounds__(256) void expT_k(const float* __restrict__ tsh,
                                              const float* __restrict__ kerF,
                                              float* __restrict__ expT) {
  int j = blockIdx.x >> 3, tile = blockIdx.x & 7;
  int t0 = tile * 256;
  const float* krow = kerF + j * KROW;
  __shared__ float kw[2304];
  __shared__ float at[256][17];
  int tid = threadIdx.x;
  int p = tid & 15, tg = tid >> 4;
  for (int i = tid; i < 2303; i += 256) kw[i] = krow[t0 + i];
  float acc[16];
#pragma unroll
  for (int i = 0; i < 16; ++i) acc[i] = 0.f;
  for (int u0 = 0; u0 < TL; u0 += 256) {
    __syncthreads();
    for (int idx = tid; idx < 4096; idx += 256) {
      int us = idx & 255, ps = idx >> 8;
      at[us][ps] = tsh[ps * TL + u0 + us];
    }
    __syncthreads();
    for (int ch = 0; ch < 16; ++ch) {
      float av[16];
#pragma unroll
      for (int rr = 0; rr < 16; ++rr) av[rr] = at[(ch << 4) + rr][p];
      float W[31];
      int wb = tg * 16 + 2047 - (u0 + (ch << 4)) - 15;
#pragma unroll
      for (int wq = 0; wq < 31; ++wq) W[wq] = kw[wb + wq];
#pragma unroll
      for (int rr = 0; rr < 16; ++rr) {
#pragma unroll
        for (int i = 0; i < 16; ++i) acc[i] = fmaf(W[15 + i - rr], av[rr], acc[i]);
      }
    }
  }
  __syncthreads();
#pragma unroll
  for (int i = 0; i < 16; ++i) at[tg * 16 + i][p] = acc[i];
  __syncthreads();
  for (int pp = 0; pp < 16; ++pp)
    expT[(pp * 64 + j) * TL + t0 + tid] = at[tid][pp];
}

// ---------------------------------------------------------------------------
// Step c: shifted masks via suffix sums. mask_j[u] = (u >= j+2)
// msk[p,j,t] = sum_{u=j+2}^{2047} kerE[p][t-u+2047]
// ---------------------------------------------------------------------------
__global__ __launch_bounds__(256) void mask_k(const float* __restrict__ kerE,
                                              float* __restrict__ msk) {
  int p = blockIdx.x >> 3, tile = blockIdx.x & 7;
  __shared__ float kw[4096];
  const float* krow = kerE + p * KROW;
  for (int i = threadIdx.x; i < 4095; i += 256) kw[i] = krow[i];
  __syncthreads();
  int t = tile * 256 + threadIdx.x;
  int base = t + 2047;
  float S = 0.f;
  for (int u = 65; u < TL; ++u) S += kw[base - u];
  float* mbase = msk + p * 64 * TL + t;
  for (int jj = 63; jj >= 0; --jj) {
    mbase[jj * TL] = S;
    S += kw[base - (jj + 1)];
  }
}

// ---------------------------------------------------------------------------
// env[p,c,t] = sum_j energy[p,c,j] * exp(-fric/(2*mass) * expT[p,j,t]) * msk[p,j,t]
// ---------------------------------------------------------------------------
__global__ __launch_bounds__(256) void env_k(const float* __restrict__ energy,
                                             const float* __restrict__ props,
                                             const float* __restrict__ expT,
                                             const float* __restrict__ msk,
                                             float* __restrict__ env) {
  int p = blockIdx.x >> 5, tile = blockIdx.x & 31;
  int tl = threadIdx.x & 63;
  int cg = threadIdx.x >> 6;
  int t = tile * 64 + tl;
  __shared__ float E[32][64];
  __shared__ float K[32];
  for (int i = threadIdx.x; i < 2048; i += 256) E[i >> 6][i & 63] = energy[p * 2048 + i];
  if (threadIdx.x < 32) {
    float mass = props[(p * 32 + threadIdx.x) * 2];
    float fric = props[(p * 32 + threadIdx.x) * 2 + 1];
    K[threadIdx.x] = fric / (2.0f * mass);
  }
  __syncthreads();
  float acc[8];
  float kk[8];
#pragma unroll
  for (int i = 0; i < 8; ++i) acc[i] = 0.f;
#pragma unroll
  for (int i = 0; i < 8; ++i) kk[i] = K[cg * 8 + i];
  const float* xrow = expT + p * 64 * TL + t;
  const float* mrow = msk + p * 64 * TL + t;
  for (int jj = 0; jj < 64; ++jj) {
    float x = xrow[jj * TL];
    float m = mrow[jj * TL];
#pragma unroll
    for (int cc = 0; cc < 8; ++cc)
      acc[cc] = fmaf(E[cg * 8 + cc][jj] * m, __expf(-kk[cc] * x), acc[cc]);
  }
#pragma unroll
  for (int cc = 0; cc < 8; ++cc)
    env[(p * 32 + cg * 8 + cc) * TL + t] = acc[cc];
}

// ---------------------------------------------------------------------------
// pos[c,T] = b_pos[c] + sum_f sin(tt[T]*freq[f]*pi) * w_pos[c,f]
// ---------------------------------------------------------------------------
__global__ __launch_bounds__(256) void pos_k(const float* __restrict__ w_pos,
                                             const float* __restrict__ b_pos,
                                             float* __restrict__ pos) {
  __shared__ float sl[32][257];
  __shared__ float wl[32][257];
  int T0 = blockIdx.x * 32;
  int tid = threadIdx.x;
  for (int idx = tid; idx < 8192; idx += 256) {
    int Tli = idx >> 8, f = idx & 255;
    float ttv = (float)(T0 + Tli) * (32768.0f / 32767.0f);
    float fr = 1e-5f + (float)f * ((0.5f - 1e-5f) / 255.0f);
    sl[Tli][f] = sinf((ttv * fr) * 3.14159265358979323846f);
  }
  for (int idx = tid; idx < 8192; idx += 256) wl[idx >> 8][idx & 255] = w_pos[idx];
  __syncthreads();
  int Tl = tid & 31, c0 = tid >> 5;
#pragma unroll
  for (int i = 0; i < 4; ++i) {
    int c = c0 + 8 * i;
    float acc = b_pos[c];
    for (int f = 0; f < 256; ++f) acc = fmaf(sl[Tl][f], wl[c][f], acc);
    pos[c * 32768 + T0 + Tl] = acc;
  }
}

// ---------------------------------------------------------------------------
// s-branch MLP: s = swapaxes(shape); 4x (s = s + relu(s)@W^T + b); relu; store [p][c][f]
// ---------------------------------------------------------------------------
__global__ __launch_bounds__(256) void sbranch_k(const float* __restrict__ shape,
                                                 const float* __restrict__ w_layers,
                                                 const float* __restrict__ b_layers,
                                                 float* __restrict__ s64) {
  __shared__ float sA[64][33];
  __shared__ float sB[64][33];
  __shared__ float W[32][33];
  __shared__ float bb[32];
  int p = blockIdx.x;
  int tid = threadIdx.x;
  for (int idx = tid; idx < 2048; idx += 256) {
    int c = idx >> 6, f = idx & 63;
    sA[f][c] = shape[p * 2048 + idx];
  }
  int c = tid & 31, fg = tid >> 5;
  for (int l = 0; l < 4; ++l) {
    for (int idx = tid; idx < 1024; idx += 256) W[idx >> 5][idx & 31] = w_layers[l * 1024 + idx];
    if (tid < 32) bb[tid] = b_layers[l * 32 + tid];
    __syncthreads();
    float(*cur)[33] = (l & 1) ? sB : sA;
    float(*nxt)[33] = (l & 1) ? sA : sB;
#pragma unroll
    for (int i = 0; i < 8; ++i) {
      int f = fg * 8 + i;
      float acc = cur[f][c] + bb[c];
#pragma unroll
      for (int k = 0; k < 32; ++k) acc = fmaf(fmaxf(cur[f][k], 0.f), W[c][k], acc);
      nxt[f][c] = acc;
    }
    __syncthreads();
  }
  for (int idx = tid; idx < 2048; idx += 256) {
    int cc = idx >> 6, f = idx & 63;
    s64[p * 2048 + idx] = fmaxf(sA[f][cc], 0.f);
  }
}

// ---------------------------------------------------------------------------
// Final: out[p,T] = sum_c pos[c,T] * lerp(s64) * relu(lerp(env))
// ---------------------------------------------------------------------------
__global__ __launch_bounds__(256) void final_k(const float* __restrict__ pos,
                                               const float* __restrict__ s64,
                                               const float* __restrict__ env,
                                               float* __restrict__ out) {
  int gid = blockIdx.x * 256 + threadIdx.x;
  int p = gid >> 15, T = gid & 32767;
  float ft = (float)T + 0.5f;
  float ce = fminf(fmaxf(ft * 0.0625f - 0.5f, 0.f), 2047.f);
  int ie = (int)ce;
  int ie1 = min(ie + 1, 2047);
  float we = ce - (float)ie;
  float cs = fminf(fmaxf(ft * (1.0f / 512.0f) - 0.5f, 0.f), 63.f);
  int is0 = (int)cs;
  int is1 = min(is0 + 1, 63);
  float ws = cs - (float)is0;
  const float* erow = env + p * 32 * TL;
  const float* srow = s64 + p * 32 * 64;
  float acc = 0.f;
  for (int c = 0; c < 32; ++c) {
    float pv = pos[c * 32768 + T];
    float ev = fmaxf(erow[c * TL + ie] * (1.f - we) + erow[c * TL + ie1] * we, 0.f);
    float sv = srow[c * 64 + is0] * (1.f - ws) + srow[c * 64 + is1] * ws;
    acc += pv * sv * ev;
  }
  out[gid] = acc;
}

extern "C" void kernel_launch(void* const* d_in, const int* in_sizes, int n_in,
                              void* d_out, int out_size, void* d_ws, size_t ws_size,
                              hipStream_t stream) {
  const float* time_in  = (const float*)d_in[0];
  const float* shifts   = (const float*)d_in[1];
  const float* energy   = (const float*)d_in[2];
  const float* shape    = (const float*)d_in[3];
  const float* props    = (const float*)d_in[4];
  const float* w_pos    = (const float*)d_in[5];
  const float* b_pos    = (const float*)d_in[6];
  const float* w_layers = (const float*)d_in[7];
  const float* b_layers = (const float*)d_in[8];

  float* ws   = (float*)d_ws;
  float* kerF = ws;                      // 64*4096
  float* kerE = kerF + 64 * 4096;        // 16*4096
  float* tsh  = kerE + 16 * 4096;        // 16*2048
  float* expT = tsh + 16 * 2048;         // 16*64*2048
  float* msk  = expT + 16 * 64 * 2048;   // 16*64*2048
  float* env  = msk + 16 * 64 * 2048;    // 16*32*2048
  float* pos  = env + 16 * 32 * 2048;    // 32*32768
  float* s64  = pos + 32 * 32768;        // 16*32*64
  float* out  = (float*)d_out;

  hipLaunchKernelGGL(build_kernels_k, dim3(80), dim3(256), 0, stream, shifts, kerF, kerE);
  hipLaunchKernelGGL(shift_time_k, dim3(128), dim3(256), 0, stream, time_in, kerE, tsh);
  hipLaunchKernelGGL(expT_k, dim3(512), dim3(256), 0, stream, tsh, kerF, expT);
  hipLaunchKernelGGL(mask_k, dim3(128), dim3(256), 0, stream, kerE, msk);
  hipLaunchKernelGGL(env_k, dim3(512), dim3(256), 0, stream, energy, props, expT, msk, env);
  hipLaunchKernelGGL(pos_k, dim3(1024), dim3(256), 0, stream, w_pos, b_pos, pos);
  hipLaunchKernelGGL(sbranch_k, dim3(16), dim3(256), 0, stream, shape, w_layers, b_layers, s64);
  hipLaunchKernelGGL(final_k, dim3(2048), dim3(256), 0, stream, pos, s64, env, out);
}

// Round 2
// 209.123 us; speedup vs baseline: 1.3031x; 1.3031x over previous
//
#include <hip/hip_runtime.h>
#include <math.h>

#define TL 2048
#define KROW 4096
#define PI_D 3.14159265358979323846

typedef __attribute__((ext_vector_type(8))) short short8v;
typedef __attribute__((ext_vector_type(4))) float float4v;

#define REPLEN 392
#define REPB (REPLEN * 2)   // 784 bytes per replica row
#define OFF_B 16384         // A-tile occupies smem[0..16384)

__device__ __forceinline__ unsigned short bf16_rne(float f) {
  unsigned u = __float_as_uint(f);
  return (unsigned short)((u + 0x7FFFu + ((u >> 16) & 1u)) >> 16);
}

// ---------------------------------------------------------------------------
// Build shift kernels. 80 blocks: b<64 frame kernels -> BFrep (bf16 hi/lo
// shift-replica G-layout); b in [64,80) event kernels -> kerE fp32 rows.
// Tap formula: k[d] = -(sin(2*pi*r)/N)*(-1)^d * cot(pi*d/N - beta),
// N=6144, beta=pi*s/3073, r=frac(3072 s/3073), s=shift*2048/3; d=0-limit -> 1.
// G[s][y] = krev[7+y-s], krev[v]=k[4094-v] => G[s][y]=k[4087-y+s] (0 outside).
// Stored with +8 guard: row index y+8, y in [-8,4088), row len 4104.
// ---------------------------------------------------------------------------
__global__ __launch_bounds__(256) void build_kernels_k(const float* __restrict__ shifts,
                                                       float* __restrict__ kerE,
                                                       unsigned short* __restrict__ BFrep) {
  __shared__ float kf[4104];  // kf[idx] = tap idx in [0,4095), zeros above
  int b = blockIdx.x;
  int tid = threadIdx.x;
  double s;
  if (b < 64) s = (double)b * (1.0 / 63.0) * (2048.0 / 3.0);
  else        s = (double)shifts[b - 64] * (2048.0 / 3.0);
  double beta = PI_D * s / 3073.0;
  double y = 3072.0 * s / 3073.0;
  double r = y - rint(y);
  double wv = -sin(2.0 * PI_D * r) / 6144.0;
  for (int idx = tid; idx < 4104; idx += 256) {
    float val = 0.0f;
    if (idx < 4095) {
      int d = idx - 2047;
      double x = PI_D * (double)d / 6144.0 - beta;
      if (fabs(x) < 1e-9) {
        val = 1.0f;
      } else {
        double c = wv * (cos(x) / sin(x));
        if (d & 1) c = -c;
        val = (float)c;
      }
    }
    kf[idx] = val;
    if (b >= 64 && idx < 4096) kerE[(b - 64) * KROW + idx] = val;
  }
  __syncthreads();
  if (b < 64) {
    for (int c = tid; c < 8192; c += 256) {
      int sel = c >> 12;            // 0=hi 1=lo
      int cc = c & 4095;
      int sr = cc >> 9;             // replica shift 0..7
      int m = cc & 511;             // 8-elem chunk
      int A = 4095 - 8 * m + sr;    // kf arg for rr=0
      unsigned short out[8];
#pragma unroll
      for (int rr = 0; rr < 8; ++rr) {
        float f = kf[A - rr];
        unsigned short hb = bf16_rne(f);
        if (sel == 0) {
          out[rr] = hb;
        } else {
          float hf = __uint_as_float(((unsigned)hb) << 16);
          out[rr] = bf16_rne(f - hf);
        }
      }
      *(short8v*)(BFrep + ((size_t)(b * 2 + sel) * 8 + sr) * 4104 + 8 * m) =
          *(short8v*)out;
    }
  }
}

// ---------------------------------------------------------------------------
// Step a: t_shift[p,t] = sum_u time[p,u] * kerE[p][t-u+2047]   (unchanged)
// ---------------------------------------------------------------------------
__global__ __launch_bounds__(256) void shift_time_k(const float* __restrict__ time_in,
                                                    const float* __restrict__ kerE,
                                                    float* __restrict__ tsh) {
  int p = blockIdx.x >> 3, tile = blockIdx.x & 7;
  __shared__ float a[TL];
  __shared__ float kw[2304];
  int t0 = tile * 256;
  const float* krow = kerE + p * KROW;
  for (int i = threadIdx.x; i < TL; i += 256) a[i] = time_in[p * TL + i];
  for (int i = threadIdx.x; i < 2303; i += 256) kw[i] = krow[t0 + i];
  __syncthreads();
  float acc = 0.f;
  int base = threadIdx.x + 2047;
#pragma unroll 8
  for (int u = 0; u < TL; ++u) acc = fmaf(a[u], kw[base - u], acc);
  tsh[p * TL + t0 + threadIdx.x] = acc;
}

// ---------------------------------------------------------------------------
// Split tsh into bf16 hi/lo planes: tsh_hl[0][..]=hi, tsh_hl[1][..]=lo
// ---------------------------------------------------------------------------
__global__ __launch_bounds__(256) void split_tsh_k(const float* __restrict__ tsh,
                                                   unsigned short* __restrict__ tsh_hl) {
  int i = blockIdx.x * 256 + threadIdx.x;  // 32768 total
  float f = tsh[i];
  unsigned short hb = bf16_rne(f);
  float hf = __uint_as_float(((unsigned)hb) << 16);
  tsh_hl[i] = hb;
  tsh_hl[32768 + i] = bf16_rne(f - hf);
}

// ---------------------------------------------------------------------------
// Step b via MFMA: expT[p,j,t] = sum_u tsh[p,u] * k_j[2047+t-u]
// Per j: C(16p x 2048t) = A(16x2048) * Toeplitz_j. 3-term bf16 hi/lo split.
// Grid: 64 j x 16 t-blocks (Tt=128). Block 256 thr = 4 waves; wave w owns
// t in [32w,32w+32) = 2 col-tiles. 8 phases of U=256 u; per phase: stage A
// (swizzled) + 8 shift-replicas of reversed kernel (from global BFrep, all
// 16B-aligned), then 8 K=32 chunks: 6 ds_read_b128 + 6 MFMA per wave.
// ---------------------------------------------------------------------------
__global__ __launch_bounds__(256, 4) void expT_mfma_k(
    const unsigned short* __restrict__ tsh_hl,
    const unsigned short* __restrict__ BFrep,
    float* __restrict__ expT) {
  __shared__ __align__(16) unsigned char smem[16384 + 2 * 8 * REPB];  // 28928 B
  int bx = blockIdx.x;
  int j = bx >> 4;
  int tB = (bx & 15) << 7;
  int tid = threadIdx.x;
  int l = tid & 63, w = tid >> 6;
  int p16 = l & 15, g = l >> 4;
  int s_rep = l & 7;
  int halfbit = (l >> 3) & 1;

  float4v acc0 = {0.f, 0.f, 0.f, 0.f};
  float4v acc1 = {0.f, 0.f, 0.f, 0.f};

  // B read base (ct=0): OFF_B + (sel*8+s)*784 + 2*i0,
  // i0 = 128 - 32w - 16ct*? ... per ct handled by -32 bytes; kc adds 64 bytes.
  int bB = OFF_B + s_rep * REPB + 256 - (halfbit << 4) + (g << 4) - (w << 6);

  const unsigned short* grow0 = BFrep + (size_t)(j * 2 + 0) * 8 * 4104;
  const unsigned short* grow1 = BFrep + (size_t)(j * 2 + 1) * 8 * 4104;

  for (int ph = 0; ph < 8; ++ph) {
    int ub = ph << 8;
    int Q8 = 1912 - tB + ub;  // = WBASE-7, multiple of 8 (can be -8)
    __syncthreads();
    // --- stage A: 2 sel x 16 p x 32 chunks of 8 bf16, XOR-swizzled
#pragma unroll
    for (int it = 0; it < 4; ++it) {
      int c = tid + (it << 8);
      int sel = c >> 9, rest = c & 511;
      int pp = rest >> 5, m = rest & 31;
      short8v v = *(const short8v*)(tsh_hl + sel * 32768 + pp * 2048 + ub + (m << 3));
      int dst = ((sel << 13) + (pp << 9) + (m << 4)) ^ ((pp & 7) << 4);
      *(short8v*)(smem + dst) = v;
    }
    // --- stage B replicas: 2 sel x 8 s x 48 chunks (i in [0,384))
#pragma unroll
    for (int it = 0; it < 3; ++it) {
      int c = tid + (it << 8);
      int sel = (c >= 384) ? 1 : 0;
      int cc = c - (sel ? 384 : 0);
      int sr = cc / 48;
      int m = cc - sr * 48;
      const unsigned short* src = (sel ? grow1 : grow0) + sr * 4104 + 8 + Q8 + (m << 3);
      short8v v = *(const short8v*)src;
      *(short8v*)(smem + OFF_B + (sel * 8 + sr) * REPB + (m << 4)) = v;
    }
    __syncthreads();
    // --- 8 K=32 chunks
#pragma unroll 2
    for (int kc = 0; kc < 8; ++kc) {
      int ao = ((p16 << 9) + (kc << 6) + (g << 4)) ^ ((p16 & 7) << 4);
      short8v ahi = *(const short8v*)(smem + ao);
      short8v alo = *(const short8v*)(smem + 8192 + ao);
      int b0 = bB + (kc << 6);
      short8v bhi0 = *(const short8v*)(smem + b0);
      short8v blo0 = *(const short8v*)(smem + b0 + 8 * REPB);
      short8v bhi1 = *(const short8v*)(smem + b0 - 32);
      short8v blo1 = *(const short8v*)(smem + b0 - 32 + 8 * REPB);
      acc0 = __builtin_amdgcn_mfma_f32_16x16x32_bf16(ahi, bhi0, acc0, 0, 0, 0);
      acc1 = __builtin_amdgcn_mfma_f32_16x16x32_bf16(ahi, bhi1, acc1, 0, 0, 0);
      acc0 = __builtin_amdgcn_mfma_f32_16x16x32_bf16(ahi, blo0, acc0, 0, 0, 0);
      acc1 = __builtin_amdgcn_mfma_f32_16x16x32_bf16(ahi, blo1, acc1, 0, 0, 0);
      acc0 = __builtin_amdgcn_mfma_f32_16x16x32_bf16(alo, bhi0, acc0, 0, 0, 0);
      acc1 = __builtin_amdgcn_mfma_f32_16x16x32_bf16(alo, bhi1, acc1, 0, 0, 0);
    }
  }
  // epilogue: C col(=t within tile)=l&15, row(=p)=g*4+r
  int t0c = tB + (w << 5) + p16;
#pragma unroll
  for (int rr = 0; rr < 4; ++rr) {
    int prow = (g << 2) + rr;
    expT[(size_t)(prow * 64 + j) * TL + t0c] = acc0[rr];
    expT[(size_t)(prow * 64 + j) * TL + t0c + 16] = acc1[rr];
  }
}

// ---------------------------------------------------------------------------
// Step c: shifted masks via suffix sums (unchanged)
// ---------------------------------------------------------------------------
__global__ __launch_bounds__(256) void mask_k(const float* __restrict__ kerE,
                                              float* __restrict__ msk) {
  int p = blockIdx.x >> 3, tile = blockIdx.x & 7;
  __shared__ float kw[4096];
  const float* krow = kerE + p * KROW;
  for (int i = threadIdx.x; i < 4095; i += 256) kw[i] = krow[i];
  __syncthreads();
  int t = tile * 256 + threadIdx.x;
  int base = t + 2047;
  float S = 0.f;
  for (int u = 65; u < TL; ++u) S += kw[base - u];
  float* mbase = msk + p * 64 * TL + t;
  for (int jj = 63; jj >= 0; --jj) {
    mbase[jj * TL] = S;
    S += kw[base - (jj + 1)];
  }
}

// ---------------------------------------------------------------------------
// env[p,c,t] = sum_j energy[p,c,j]*exp(-fric/(2 mass)*expT[p,j,t])*msk[p,j,t]
// ---------------------------------------------------------------------------
__global__ __launch_bounds__(256) void env_k(const float* __restrict__ energy,
                                             const float* __restrict__ props,
                                             const float* __restrict__ expT,
                                             const float* __restrict__ msk,
                                             float* __restrict__ env) {
  int p = blockIdx.x >> 5, tile = blockIdx.x & 31;
  int tl = threadIdx.x & 63;
  int cg = threadIdx.x >> 6;
  int t = tile * 64 + tl;
  __shared__ float E[32][64];
  __shared__ float K[32];
  for (int i = threadIdx.x; i < 2048; i += 256) E[i >> 6][i & 63] = energy[p * 2048 + i];
  if (threadIdx.x < 32) {
    float mass = props[(p * 32 + threadIdx.x) * 2];
    float fric = props[(p * 32 + threadIdx.x) * 2 + 1];
    K[threadIdx.x] = fric / (2.0f * mass);
  }
  __syncthreads();
  float acc[8];
  float kk[8];
#pragma unroll
  for (int i = 0; i < 8; ++i) acc[i] = 0.f;
#pragma unroll
  for (int i = 0; i < 8; ++i) kk[i] = K[cg * 8 + i];
  const float* xrow = expT + p * 64 * TL + t;
  const float* mrow = msk + p * 64 * TL + t;
  for (int jj = 0; jj < 64; ++jj) {
    float x = xrow[jj * TL];
    float m = mrow[jj * TL];
#pragma unroll
    for (int cc = 0; cc < 8; ++cc)
      acc[cc] = fmaf(E[cg * 8 + cc][jj] * m, __expf(-kk[cc] * x), acc[cc]);
  }
#pragma unroll
  for (int cc = 0; cc < 8; ++cc)
    env[(p * 32 + cg * 8 + cc) * TL + t] = acc[cc];
}

// ---------------------------------------------------------------------------
// pos[c,T] = b_pos[c] + sum_f sin(tt[T]*freq[f]*pi) * w_pos[c,f]  (unchanged)
// ---------------------------------------------------------------------------
__global__ __launch_bounds__(256) void pos_k(const float* __restrict__ w_pos,
                                             const float* __restrict__ b_pos,
                                             float* __restrict__ pos) {
  __shared__ float sl[32][257];
  __shared__ float wl[32][257];
  int T0 = blockIdx.x * 32;
  int tid = threadIdx.x;
  for (int idx = tid; idx < 8192; idx += 256) {
    int Tli = idx >> 8, f = idx & 255;
    float ttv = (float)(T0 + Tli) * (32768.0f / 32767.0f);
    float fr = 1e-5f + (float)f * ((0.5f - 1e-5f) / 255.0f);
    sl[Tli][f] = sinf((ttv * fr) * 3.14159265358979323846f);
  }
  for (int idx = tid; idx < 8192; idx += 256) wl[idx >> 8][idx & 255] = w_pos[idx];
  __syncthreads();
  int Tl = tid & 31, c0 = tid >> 5;
#pragma unroll
  for (int i = 0; i < 4; ++i) {
    int c = c0 + 8 * i;
    float acc = b_pos[c];
    for (int f = 0; f < 256; ++f) acc = fmaf(sl[Tl][f], wl[c][f], acc);
    pos[c * 32768 + T0 + Tl] = acc;
  }
}

// ---------------------------------------------------------------------------
// s-branch MLP (unchanged)
// ---------------------------------------------------------------------------
__global__ __launch_bounds__(256) void sbranch_k(const float* __restrict__ shape,
                                                 const float* __restrict__ w_layers,
                                                 const float* __restrict__ b_layers,
                                                 float* __restrict__ s64) {
  __shared__ float sA[64][33];
  __shared__ float sB[64][33];
  __shared__ float W[32][33];
  __shared__ float bb[32];
  int p = blockIdx.x;
  int tid = threadIdx.x;
  for (int idx = tid; idx < 2048; idx += 256) {
    int c = idx >> 6, f = idx & 63;
    sA[f][c] = shape[p * 2048 + idx];
  }
  int c = tid & 31, fg = tid >> 5;
  for (int l = 0; l < 4; ++l) {
    for (int idx = tid; idx < 1024; idx += 256) W[idx >> 5][idx & 31] = w_layers[l * 1024 + idx];
    if (tid < 32) bb[tid] = b_layers[l * 32 + tid];
    __syncthreads();
    float(*cur)[33] = (l & 1) ? sB : sA;
    float(*nxt)[33] = (l & 1) ? sA : sB;
#pragma unroll
    for (int i = 0; i < 8; ++i) {
      int f = fg * 8 + i;
      float acc = cur[f][c] + bb[c];
#pragma unroll
      for (int k = 0; k < 32; ++k) acc = fmaf(fmaxf(cur[f][k], 0.f), W[c][k], acc);
      nxt[f][c] = acc;
    }
    __syncthreads();
  }
  for (int idx = tid; idx < 2048; idx += 256) {
    int cc = idx >> 6, f = idx & 63;
    s64[p * 2048 + idx] = fmaxf(sA[f][cc], 0.f);
  }
}

// ---------------------------------------------------------------------------
// Final (unchanged)
// ---------------------------------------------------------------------------
__global__ __launch_bounds__(256) void final_k(const float* __restrict__ pos,
                                               const float* __restrict__ s64,
                                               const float* __restrict__ env,
                                               float* __restrict__ out) {
  int gid = blockIdx.x * 256 + threadIdx.x;
  int p = gid >> 15, T = gid & 32767;
  float ft = (float)T + 0.5f;
  float ce = fminf(fmaxf(ft * 0.0625f - 0.5f, 0.f), 2047.f);
  int ie = (int)ce;
  int ie1 = min(ie + 1, 2047);
  float we = ce - (float)ie;
  float cs = fminf(fmaxf(ft * (1.0f / 512.0f) - 0.5f, 0.f), 63.f);
  int is0 = (int)cs;
  int is1 = min(is0 + 1, 63);
  float ws = cs - (float)is0;
  const float* erow = env + p * 32 * TL;
  const float* srow = s64 + p * 32 * 64;
  float acc = 0.f;
  for (int c = 0; c < 32; ++c) {
    float pv = pos[c * 32768 + T];
    float ev = fmaxf(erow[c * TL + ie] * (1.f - we) + erow[c * TL + ie1] * we, 0.f);
    float sv = srow[c * 64 + is0] * (1.f - ws) + srow[c * 64 + is1] * ws;
    acc += pv * sv * ev;
  }
  out[gid] = acc;
}

extern "C" void kernel_launch(void* const* d_in, const int* in_sizes, int n_in,
                              void* d_out, int out_size, void* d_ws, size_t ws_size,
                              hipStream_t stream) {
  const float* time_in  = (const float*)d_in[0];
  const float* shifts   = (const float*)d_in[1];
  const float* energy   = (const float*)d_in[2];
  const float* shape    = (const float*)d_in[3];
  const float* props    = (const float*)d_in[4];
  const float* w_pos    = (const float*)d_in[5];
  const float* b_pos    = (const float*)d_in[6];
  const float* w_layers = (const float*)d_in[7];
  const float* b_layers = (const float*)d_in[8];

  float* ws = (float*)d_ws;
  float* kerE = ws;                                   // 65536 f
  unsigned short* BFrep = (unsigned short*)(ws + 65536);  // 64*2*8*4104 u16 = 2101248 f
  float* tsh  = ws + 65536 + 2101248;                 // 32768 f
  unsigned short* tsh_hl = (unsigned short*)(ws + 2199552); // 65536 u16 = 32768 f
  float* expT = ws + 2232320;                         // 2097152 f
  float* msk  = ws + 4329472;                         // 2097152 f
  float* env  = ws + 6426624;                         // 1048576 f
  // pos & s64 alias the BFrep region (dead after expT_mfma_k)
  float* pos  = ws + 65536;                           // 1048576 f
  float* s64  = ws + 65536 + 1048576;                 // 32768 f
  float* out  = (float*)d_out;

  hipLaunchKernelGGL(build_kernels_k, dim3(80), dim3(256), 0, stream, shifts, kerE, BFrep);
  hipLaunchKernelGGL(shift_time_k, dim3(128), dim3(256), 0, stream, time_in, kerE, tsh);
  hipLaunchKernelGGL(split_tsh_k, dim3(128), dim3(256), 0, stream, tsh, tsh_hl);
  hipLaunchKernelGGL(expT_mfma_k, dim3(1024), dim3(256), 0, stream, tsh_hl, BFrep, expT);
  hipLaunchKernelGGL(mask_k, dim3(128), dim3(256), 0, stream, kerE, msk);
  hipLaunchKernelGGL(env_k, dim3(512), dim3(256), 0, stream, energy, props, expT, msk, env);
  hipLaunchKernelGGL(pos_k, dim3(1024), dim3(256), 0, stream, w_pos, b_pos, pos);
  hipLaunchKernelGGL(sbranch_k, dim3(16), dim3(256), 0, stream, shape, w_layers, b_layers, s64);
  hipLaunchKernelGGL(final_k, dim3(2048), dim3(256), 0, stream, pos, s64, env, out);
}

// Round 3
// 181.947 us; speedup vs baseline: 1.4977x; 1.1494x over previous
//
#include <hip/hip_runtime.h>
#include <math.h>

#define TL 2048
#define KROW 4096
#define PI_D 3.14159265358979323846

typedef __attribute__((ext_vector_type(8))) short short8v;
typedef __attribute__((ext_vector_type(4))) float float4v;

#define REPLEN 392
#define REPB (REPLEN * 2)   // 784 bytes per replica row
#define OFF_B 16384         // A-tile occupies smem[0..16384)

__device__ __forceinline__ unsigned short bf16_rne(float f) {
  unsigned u = __float_as_uint(f);
  return (unsigned short)((u + 0x7FFFu + ((u >> 16) & 1u)) >> 16);
}

// ---------------------------------------------------------------------------
// Build shift kernels. 80 blocks: b<64 frame kernels -> BFrep (bf16 hi/lo
// shift-replica G-layout); b in [64,80) event kernels -> kerE fp32 rows.
// k[d] = -(sin(2*pi*r)/N)*(-1)^d * cot(pi*d/N - beta), N=6144,
// beta=pi*s/3073, r=frac(3072 s/3073), s=shift*2048/3; d->0 limit = 1.
// ---------------------------------------------------------------------------
__global__ __launch_bounds__(256) void build_kernels_k(const float* __restrict__ shifts,
                                                       float* __restrict__ kerE,
                                                       unsigned short* __restrict__ BFrep) {
  __shared__ float kf[4104];
  int b = blockIdx.x;
  int tid = threadIdx.x;
  double s;
  if (b < 64) s = (double)b * (1.0 / 63.0) * (2048.0 / 3.0);
  else        s = (double)shifts[b - 64] * (2048.0 / 3.0);
  double beta = PI_D * s / 3073.0;
  double y = 3072.0 * s / 3073.0;
  double r = y - rint(y);
  double wv = -sin(2.0 * PI_D * r) / 6144.0;
  for (int idx = tid; idx < 4104; idx += 256) {
    float val = 0.0f;
    if (idx < 4095) {
      int d = idx - 2047;
      double x = PI_D * (double)d / 6144.0 - beta;
      if (fabs(x) < 1e-9) {
        val = 1.0f;
      } else {
        double c = wv * (cos(x) / sin(x));
        if (d & 1) c = -c;
        val = (float)c;
      }
    }
    kf[idx] = val;
    if (b >= 64 && idx < 4096) kerE[(b - 64) * KROW + idx] = val;
  }
  __syncthreads();
  if (b < 64) {
    for (int c = tid; c < 8192; c += 256) {
      int sel = c >> 12;
      int cc = c & 4095;
      int sr = cc >> 9;
      int m = cc & 511;
      int A = 4095 - 8 * m + sr;
      unsigned short out[8];
#pragma unroll
      for (int rr = 0; rr < 8; ++rr) {
        float f = kf[A - rr];
        unsigned short hb = bf16_rne(f);
        if (sel == 0) {
          out[rr] = hb;
        } else {
          float hf = __uint_as_float(((unsigned)hb) << 16);
          out[rr] = bf16_rne(f - hf);
        }
      }
      *(short8v*)(BFrep + ((size_t)(b * 2 + sel) * 8 + sr) * 4104 + 8 * m) =
          *(short8v*)out;
    }
  }
}

// ---------------------------------------------------------------------------
// Step a: t_shift[p,t] = sum_u time[p,u]*kerE[p][t-u+2047]; writes bf16 hi/lo
// planes directly (split_tsh fused here).
// ---------------------------------------------------------------------------
__global__ __launch_bounds__(256) void shift_time_k(const float* __restrict__ time_in,
                                                    const float* __restrict__ kerE,
                                                    unsigned short* __restrict__ tsh_hl) {
  int p = blockIdx.x >> 3, tile = blockIdx.x & 7;
  __shared__ float a[TL];
  __shared__ float kw[2304];
  int t0 = tile * 256;
  const float* krow = kerE + p * KROW;
  for (int i = threadIdx.x; i < TL; i += 256) a[i] = time_in[p * TL + i];
  for (int i = threadIdx.x; i < 2303; i += 256) kw[i] = krow[t0 + i];
  __syncthreads();
  float acc = 0.f;
  int base = threadIdx.x + 2047;
#pragma unroll 8
  for (int u = 0; u < TL; ++u) acc = fmaf(a[u], kw[base - u], acc);
  unsigned short hb = bf16_rne(acc);
  float hf = __uint_as_float(((unsigned)hb) << 16);
  tsh_hl[p * TL + t0 + threadIdx.x] = hb;
  tsh_hl[32768 + p * TL + t0 + threadIdx.x] = bf16_rne(acc - hf);
}

// ---------------------------------------------------------------------------
// Step b via MFMA (unchanged from round 2)
// ---------------------------------------------------------------------------
__global__ __launch_bounds__(256, 4) void expT_mfma_k(
    const unsigned short* __restrict__ tsh_hl,
    const unsigned short* __restrict__ BFrep,
    float* __restrict__ expT) {
  __shared__ __align__(16) unsigned char smem[16384 + 2 * 8 * REPB];
  int bx = blockIdx.x;
  int j = bx >> 4;
  int tB = (bx & 15) << 7;
  int tid = threadIdx.x;
  int l = tid & 63, w = tid >> 6;
  int p16 = l & 15, g = l >> 4;
  int s_rep = l & 7;
  int halfbit = (l >> 3) & 1;

  float4v acc0 = {0.f, 0.f, 0.f, 0.f};
  float4v acc1 = {0.f, 0.f, 0.f, 0.f};

  int bB = OFF_B + s_rep * REPB + 256 - (halfbit << 4) + (g << 4) - (w << 6);

  const unsigned short* grow0 = BFrep + (size_t)(j * 2 + 0) * 8 * 4104;
  const unsigned short* grow1 = BFrep + (size_t)(j * 2 + 1) * 8 * 4104;

  for (int ph = 0; ph < 8; ++ph) {
    int ub = ph << 8;
    int Q8 = 1912 - tB + ub;
    __syncthreads();
#pragma unroll
    for (int it = 0; it < 4; ++it) {
      int c = tid + (it << 8);
      int sel = c >> 9, rest = c & 511;
      int pp = rest >> 5, m = rest & 31;
      short8v v = *(const short8v*)(tsh_hl + sel * 32768 + pp * 2048 + ub + (m << 3));
      int dst = ((sel << 13) + (pp << 9) + (m << 4)) ^ ((pp & 7) << 4);
      *(short8v*)(smem + dst) = v;
    }
#pragma unroll
    for (int it = 0; it < 3; ++it) {
      int c = tid + (it << 8);
      int sel = (c >= 384) ? 1 : 0;
      int cc = c - (sel ? 384 : 0);
      int sr = cc / 48;
      int m = cc - sr * 48;
      const unsigned short* src = (sel ? grow1 : grow0) + sr * 4104 + 8 + Q8 + (m << 3);
      short8v v = *(const short8v*)src;
      *(short8v*)(smem + OFF_B + (sel * 8 + sr) * REPB + (m << 4)) = v;
    }
    __syncthreads();
#pragma unroll 2
    for (int kc = 0; kc < 8; ++kc) {
      int ao = ((p16 << 9) + (kc << 6) + (g << 4)) ^ ((p16 & 7) << 4);
      short8v ahi = *(const short8v*)(smem + ao);
      short8v alo = *(const short8v*)(smem + 8192 + ao);
      int b0 = bB + (kc << 6);
      short8v bhi0 = *(const short8v*)(smem + b0);
      short8v blo0 = *(const short8v*)(smem + b0 + 8 * REPB);
      short8v bhi1 = *(const short8v*)(smem + b0 - 32);
      short8v blo1 = *(const short8v*)(smem + b0 - 32 + 8 * REPB);
      acc0 = __builtin_amdgcn_mfma_f32_16x16x32_bf16(ahi, bhi0, acc0, 0, 0, 0);
      acc1 = __builtin_amdgcn_mfma_f32_16x16x32_bf16(ahi, bhi1, acc1, 0, 0, 0);
      acc0 = __builtin_amdgcn_mfma_f32_16x16x32_bf16(ahi, blo0, acc0, 0, 0, 0);
      acc1 = __builtin_amdgcn_mfma_f32_16x16x32_bf16(ahi, blo1, acc1, 0, 0, 0);
      acc0 = __builtin_amdgcn_mfma_f32_16x16x32_bf16(alo, bhi0, acc0, 0, 0, 0);
      acc1 = __builtin_amdgcn_mfma_f32_16x16x32_bf16(alo, bhi1, acc1, 0, 0, 0);
    }
  }
  int t0c = tB + (w << 5) + p16;
#pragma unroll
  for (int rr = 0; rr < 4; ++rr) {
    int prow = (g << 2) + rr;
    expT[(size_t)(prow * 64 + j) * TL + t0c] = acc0[rr];
    expT[(size_t)(prow * 64 + j) * TL + t0c + 16] = acc1[rr];
  }
}

// ---------------------------------------------------------------------------
// Step c: shifted masks via suffix sums (unchanged)
// ---------------------------------------------------------------------------
__global__ __launch_bounds__(256) void mask_k(const float* __restrict__ kerE,
                                              float* __restrict__ msk) {
  int p = blockIdx.x >> 3, tile = blockIdx.x & 7;
  __shared__ float kw[4096];
  const float* krow = kerE + p * KROW;
  for (int i = threadIdx.x; i < 4095; i += 256) kw[i] = krow[i];
  __syncthreads();
  int t = tile * 256 + threadIdx.x;
  int base = t + 2047;
  float S = 0.f;
  for (int u = 65; u < TL; ++u) S += kw[base - u];
  float* mbase = msk + p * 64 * TL + t;
  for (int jj = 63; jj >= 0; --jj) {
    mbase[jj * TL] = S;
    S += kw[base - (jj + 1)];
  }
}

// ---------------------------------------------------------------------------
// env (unchanged)
// ---------------------------------------------------------------------------
__global__ __launch_bounds__(256) void env_k(const float* __restrict__ energy,
                                             const float* __restrict__ props,
                                             const float* __restrict__ expT,
                                             const float* __restrict__ msk,
                                             float* __restrict__ env) {
  int p = blockIdx.x >> 5, tile = blockIdx.x & 31;
  int tl = threadIdx.x & 63;
  int cg = threadIdx.x >> 6;
  int t = tile * 64 + tl;
  __shared__ float E[32][64];
  __shared__ float K[32];
  for (int i = threadIdx.x; i < 2048; i += 256) E[i >> 6][i & 63] = energy[p * 2048 + i];
  if (threadIdx.x < 32) {
    float mass = props[(p * 32 + threadIdx.x) * 2];
    float fric = props[(p * 32 + threadIdx.x) * 2 + 1];
    K[threadIdx.x] = fric / (2.0f * mass);
  }
  __syncthreads();
  float acc[8];
  float kk[8];
#pragma unroll
  for (int i = 0; i < 8; ++i) acc[i] = 0.f;
#pragma unroll
  for (int i = 0; i < 8; ++i) kk[i] = K[cg * 8 + i];
  const float* xrow = expT + p * 64 * TL + t;
  const float* mrow = msk + p * 64 * TL + t;
  for (int jj = 0; jj < 64; ++jj) {
    float x = xrow[jj * TL];
    float m = mrow[jj * TL];
#pragma unroll
    for (int cc = 0; cc < 8; ++cc)
      acc[cc] = fmaf(E[cg * 8 + cc][jj] * m, __expf(-kk[cc] * x), acc[cc]);
  }
#pragma unroll
  for (int cc = 0; cc < 8; ++cc)
    env[(p * 32 + cg * 8 + cc) * TL + t] = acc[cc];
}

// ---------------------------------------------------------------------------
// pos via MFMA: pos[c,T] = b[c] + S(T x 256f) @ W^T(256f x 32c).
// A-frag sins computed in registers via v_fract+v_sin (revolutions =
// fl(tt*fr)/2, exact halving). B-frags (W hi/lo bf16) preloaded to regs
// from global. 3-term hi/lo split. No LDS, no barriers.
// Wave w of block handles T-tile [T0,T0+16); block covers 64 T.
// ---------------------------------------------------------------------------
__global__ __launch_bounds__(256) void pos_mfma_k(const float* __restrict__ w_pos,
                                                  const float* __restrict__ b_pos,
                                                  float* __restrict__ pos) {
  int tid = threadIdx.x;
  int l = tid & 63, w = tid >> 6;
  int p16 = l & 15, g = l >> 4;
  int T0 = blockIdx.x * 64 + w * 16;

  short8v bhi0[8], blo0[8], bhi1[8], blo1[8];
#pragma unroll
  for (int kc = 0; kc < 8; ++kc) {
#pragma unroll
    for (int ct = 0; ct < 2; ++ct) {
      const float* wrow = w_pos + (ct * 16 + p16) * 256 + kc * 32 + g * 8;
      float4v w0 = *(const float4v*)(wrow);
      float4v w1 = *(const float4v*)(wrow + 4);
      short8v hv, lv;
#pragma unroll
      for (int i = 0; i < 8; ++i) {
        float vv = (i < 4) ? w0[i] : w1[i - 4];
        unsigned short hb = bf16_rne(vv);
        float hf = __uint_as_float(((unsigned)hb) << 16);
        hv[i] = (short)hb;
        lv[i] = (short)bf16_rne(vv - hf);
      }
      if (ct == 0) { bhi0[kc] = hv; blo0[kc] = lv; }
      else         { bhi1[kc] = hv; blo1[kc] = lv; }
    }
  }

  float ttv = (float)(T0 + p16) * (32768.0f / 32767.0f);
  float4v acc0 = {0.f, 0.f, 0.f, 0.f};
  float4v acc1 = {0.f, 0.f, 0.f, 0.f};
#pragma unroll
  for (int kc = 0; kc < 8; ++kc) {
    short8v ahi, alo;
#pragma unroll
    for (int i = 0; i < 8; ++i) {
      int f = kc * 32 + g * 8 + i;
      float fr = 1e-5f + (float)f * ((0.5f - 1e-5f) / 255.0f);
      float rev = ttv * (0.5f * fr);
      float sv = __builtin_amdgcn_sinf(__builtin_amdgcn_fractf(rev));
      unsigned short hb = bf16_rne(sv);
      float hf = __uint_as_float(((unsigned)hb) << 16);
      ahi[i] = (short)hb;
      alo[i] = (short)bf16_rne(sv - hf);
    }
    acc0 = __builtin_amdgcn_mfma_f32_16x16x32_bf16(ahi, bhi0[kc], acc0, 0, 0, 0);
    acc1 = __builtin_amdgcn_mfma_f32_16x16x32_bf16(ahi, bhi1[kc], acc1, 0, 0, 0);
    acc0 = __builtin_amdgcn_mfma_f32_16x16x32_bf16(ahi, blo0[kc], acc0, 0, 0, 0);
    acc1 = __builtin_amdgcn_mfma_f32_16x16x32_bf16(ahi, blo1[kc], acc1, 0, 0, 0);
    acc0 = __builtin_amdgcn_mfma_f32_16x16x32_bf16(alo, bhi0[kc], acc0, 0, 0, 0);
    acc1 = __builtin_amdgcn_mfma_f32_16x16x32_bf16(alo, bhi1[kc], acc1, 0, 0, 0);
  }
  float bp0 = b_pos[p16], bp1 = b_pos[16 + p16];
  float4v o0, o1;
#pragma unroll
  for (int rr = 0; rr < 4; ++rr) {
    o0[rr] = acc0[rr] + bp0;
    o1[rr] = acc1[rr] + bp1;
  }
  int Tr = T0 + g * 4;
  *(float4v*)(pos + (size_t)p16 * 32768 + Tr) = o0;
  *(float4v*)(pos + (size_t)(16 + p16) * 32768 + Tr) = o1;
}

// ---------------------------------------------------------------------------
// s-branch MLP (unchanged)
// ---------------------------------------------------------------------------
__global__ __launch_bounds__(256) void sbranch_k(const float* __restrict__ shape,
                                                 const float* __restrict__ w_layers,
                                                 const float* __restrict__ b_layers,
                                                 float* __restrict__ s64) {
  __shared__ float sA[64][33];
  __shared__ float sB[64][33];
  __shared__ float W[32][33];
  __shared__ float bb[32];
  int p = blockIdx.x;
  int tid = threadIdx.x;
  for (int idx = tid; idx < 2048; idx += 256) {
    int c = idx >> 6, f = idx & 63;
    sA[f][c] = shape[p * 2048 + idx];
  }
  int c = tid & 31, fg = tid >> 5;
  for (int l = 0; l < 4; ++l) {
    for (int idx = tid; idx < 1024; idx += 256) W[idx >> 5][idx & 31] = w_layers[l * 1024 + idx];
    if (tid < 32) bb[tid] = b_layers[l * 32 + tid];
    __syncthreads();
    float(*cur)[33] = (l & 1) ? sB : sA;
    float(*nxt)[33] = (l & 1) ? sA : sB;
#pragma unroll
    for (int i = 0; i < 8; ++i) {
      int f = fg * 8 + i;
      float acc = cur[f][c] + bb[c];
#pragma unroll
      for (int k = 0; k < 32; ++k) acc = fmaf(fmaxf(cur[f][k], 0.f), W[c][k], acc);
      nxt[f][c] = acc;
    }
    __syncthreads();
  }
  for (int idx = tid; idx < 2048; idx += 256) {
    int cc = idx >> 6, f = idx & 63;
    s64[p * 2048 + idx] = fmaxf(sA[f][cc], 0.f);
  }
}

// ---------------------------------------------------------------------------
// Final (unchanged)
// ---------------------------------------------------------------------------
__global__ __launch_bounds__(256) void final_k(const float* __restrict__ pos,
                                               const float* __restrict__ s64,
                                               const float* __restrict__ env,
                                               float* __restrict__ out) {
  int gid = blockIdx.x * 256 + threadIdx.x;
  int p = gid >> 15, T = gid & 32767;
  float ft = (float)T + 0.5f;
  float ce = fminf(fmaxf(ft * 0.0625f - 0.5f, 0.f), 2047.f);
  int ie = (int)ce;
  int ie1 = min(ie + 1, 2047);
  float we = ce - (float)ie;
  float cs = fminf(fmaxf(ft * (1.0f / 512.0f) - 0.5f, 0.f), 63.f);
  int is0 = (int)cs;
  int is1 = min(is0 + 1, 63);
  float ws = cs - (float)is0;
  const float* erow = env + p * 32 * TL;
  const float* srow = s64 + p * 32 * 64;
  float acc = 0.f;
  for (int c = 0; c < 32; ++c) {
    float pv = pos[c * 32768 + T];
    float ev = fmaxf(erow[c * TL + ie] * (1.f - we) + erow[c * TL + ie1] * we, 0.f);
    float sv = srow[c * 64 + is0] * (1.f - ws) + srow[c * 64 + is1] * ws;
    acc += pv * sv * ev;
  }
  out[gid] = acc;
}

extern "C" void kernel_launch(void* const* d_in, const int* in_sizes, int n_in,
                              void* d_out, int out_size, void* d_ws, size_t ws_size,
                              hipStream_t stream) {
  const float* time_in  = (const float*)d_in[0];
  const float* shifts   = (const float*)d_in[1];
  const float* energy   = (const float*)d_in[2];
  const float* shape    = (const float*)d_in[3];
  const float* props    = (const float*)d_in[4];
  const float* w_pos    = (const float*)d_in[5];
  const float* b_pos    = (const float*)d_in[6];
  const float* w_layers = (const float*)d_in[7];
  const float* b_layers = (const float*)d_in[8];

  float* ws = (float*)d_ws;
  float* kerE = ws;                                   // 65536 f
  unsigned short* BFrep = (unsigned short*)(ws + 65536);  // 2101248 f
  unsigned short* tsh_hl = (unsigned short*)(ws + 2199552); // 32768 f
  float* expT = ws + 2232320;                         // 2097152 f
  float* msk  = ws + 4329472;                         // 2097152 f
  float* env  = ws + 6426624;                         // 1048576 f
  // pos & s64 alias the BFrep region (dead after expT_mfma_k)
  float* pos  = ws + 65536;                           // 1048576 f
  float* s64  = ws + 65536 + 1048576;                 // 32768 f
  float* out  = (float*)d_out;

  hipLaunchKernelGGL(build_kernels_k, dim3(80), dim3(256), 0, stream, shifts, kerE, BFrep);
  hipLaunchKernelGGL(shift_time_k, dim3(128), dim3(256), 0, stream, time_in, kerE, tsh_hl);
  hipLaunchKernelGGL(expT_mfma_k, dim3(1024), dim3(256), 0, stream, tsh_hl, BFrep, expT);
  hipLaunchKernelGGL(mask_k, dim3(128), dim3(256), 0, stream, kerE, msk);
  hipLaunchKernelGGL(env_k, dim3(512), dim3(256), 0, stream, energy, props, expT, msk, env);
  hipLaunchKernelGGL(pos_mfma_k, dim3(512), dim3(256), 0, stream, w_pos, b_pos, pos);
  hipLaunchKernelGGL(sbranch_k, dim3(16), dim3(256), 0, stream, shape, w_layers, b_layers, s64);
  hipLaunchKernelGGL(final_k, dim3(2048), dim3(256), 0, stream, pos, s64, env, out);
}

// Round 4
// 118.014 us; speedup vs baseline: 2.3091x; 1.5417x over previous
//
#include <hip/hip_runtime.h>
#include <math.h>

#define TL 2048
#define KROW 4096
#define PI_D 3.14159265358979323846

typedef __attribute__((ext_vector_type(8))) short short8v;
typedef __attribute__((ext_vector_type(4))) float float4v;

#define REPLEN 392
#define REPB (REPLEN * 2)   // 784 bytes per replica row
#define OFF_B 8192          // A-tile occupies smem[0..8192)

__device__ __forceinline__ unsigned short bf16_rne(float f) {
  unsigned u = __float_as_uint(f);
  return (unsigned short)((u + 0x7FFFu + ((u >> 16) & 1u)) >> 16);
}

// ---------------------------------------------------------------------------
// Build shift kernels. 80 blocks: b<64 frame kernels -> BFrep (single-plane
// bf16 shift-replica G-layout); b in [64,80) event kernels -> kerE fp32 rows
// + kerC exclusive prefix (for the shifted step-mask identity).
// k[d] = -(sin(2*pi*r)/N)*(-1)^d * cot(pi*d/N - beta), N=6144,
// beta=pi*s/3073, r=frac(3072 s/3073), s=shift*2048/3; d->0 limit = 1.
// ---------------------------------------------------------------------------
__global__ __launch_bounds__(256) void build_kernels_k(const float* __restrict__ shifts,
                                                       float* __restrict__ kerE,
                                                       float* __restrict__ kerC,
                                                       unsigned short* __restrict__ BFrep) {
  __shared__ float kf[4104];
  __shared__ float wsum[4];
  int b = blockIdx.x;
  int tid = threadIdx.x;
  double s;
  if (b < 64) s = (double)b * (1.0 / 63.0) * (2048.0 / 3.0);
  else        s = (double)shifts[b - 64] * (2048.0 / 3.0);
  double beta = PI_D * s / 3073.0;
  double y = 3072.0 * s / 3073.0;
  double r = y - rint(y);
  double wv = -sin(2.0 * PI_D * r) / 6144.0;
  for (int idx = tid; idx < 4104; idx += 256) {
    float val = 0.0f;
    if (idx < 4095) {
      int d = idx - 2047;
      double x = PI_D * (double)d / 6144.0 - beta;
      if (fabs(x) < 1e-9) {
        val = 1.0f;
      } else {
        double c = wv * (cos(x) / sin(x));
        if (d & 1) c = -c;
        val = (float)c;
      }
    }
    kf[idx] = val;
    if (b >= 64 && idx < 4096) kerE[(b - 64) * KROW + idx] = val;
  }
  __syncthreads();
  if (b < 64) {
    // single-plane bf16 replicas
    for (int c = tid; c < 4096; c += 256) {
      int sr = c >> 9;
      int m = c & 511;
      int A = 4095 - 8 * m + sr;
      unsigned short out[8];
#pragma unroll
      for (int rr = 0; rr < 8; ++rr) out[rr] = bf16_rne(kf[A - rr]);
      *(short8v*)(BFrep + ((size_t)(b * 8 + sr)) * 4104 + 8 * m) = *(short8v*)out;
    }
  } else {
    // exclusive prefix of kf[0..4095] -> kerC
    float s0 = 0.f;
    int base = tid * 16;
#pragma unroll
    for (int i = 0; i < 16; ++i) s0 += kf[base + i];
    int lane = tid & 63;
    float v = s0;
#pragma unroll
    for (int d = 1; d < 64; d <<= 1) {
      float o = __shfl_up(v, (unsigned)d, 64);
      if (lane >= d) v += o;
    }
    if (lane == 63) wsum[tid >> 6] = v;
    __syncthreads();
    float woff = 0.f;
    for (int k = 0; k < (tid >> 6); ++k) woff += wsum[k];
    float run = v + woff - s0;  // exclusive prefix at chunk start
    float* crow = kerC + (b - 64) * 4096;
#pragma unroll
    for (int i = 0; i < 16; ++i) {
      crow[base + i] = run;
      run += kf[base + i];
    }
  }
}

// ---------------------------------------------------------------------------
// Step a: t_shift[p,t] = sum_u time[p,u]*kerE[p][t-u+2047]; writes bf16.
// ---------------------------------------------------------------------------
__global__ __launch_bounds__(256) void shift_time_k(const float* __restrict__ time_in,
                                                    const float* __restrict__ kerE,
                                                    unsigned short* __restrict__ tsh_b) {
  int p = blockIdx.x >> 3, tile = blockIdx.x & 7;
  __shared__ float a[TL];
  __shared__ float kw[2304];
  int t0 = tile * 256;
  const float* krow = kerE + p * KROW;
  for (int i = threadIdx.x; i < TL; i += 256) a[i] = time_in[p * TL + i];
  for (int i = threadIdx.x; i < 2303; i += 256) kw[i] = krow[t0 + i];
  __syncthreads();
  float acc = 0.f;
  int base = threadIdx.x + 2047;
#pragma unroll 8
  for (int u = 0; u < TL; ++u) acc = fmaf(a[u], kw[base - u], acc);
  tsh_b[p * TL + t0 + threadIdx.x] = bf16_rne(acc);
}

// ---------------------------------------------------------------------------
// Step b via MFMA, single bf16: expT[p,j,t] = sum_u tsh[p,u]*k_j[2047+t-u].
// Per kc: 1 A-read + 2 B-reads, 2 MFMA. LDS 14.5 KB.
// ---------------------------------------------------------------------------
__global__ __launch_bounds__(256, 4) void expT_mfma_k(
    const unsigned short* __restrict__ tsh_b,
    const unsigned short* __restrict__ BFrep,
    float* __restrict__ expT) {
  __shared__ __align__(16) unsigned char smem[8192 + 8 * REPB];  // 14464 B
  int bx = blockIdx.x;
  int j = bx >> 4;
  int tB = (bx & 15) << 7;
  int tid = threadIdx.x;
  int l = tid & 63, w = tid >> 6;
  int p16 = l & 15, g = l >> 4;
  int s_rep = l & 7;
  int halfbit = (l >> 3) & 1;

  float4v acc0 = {0.f, 0.f, 0.f, 0.f};
  float4v acc1 = {0.f, 0.f, 0.f, 0.f};

  int bB = OFF_B + s_rep * REPB + 256 - (halfbit << 4) + (g << 4) - (w << 6);
  const unsigned short* grow = BFrep + (size_t)j * 8 * 4104;

  for (int ph = 0; ph < 8; ++ph) {
    int ub = ph << 8;
    int Q8 = 1912 - tB + ub;
    __syncthreads();
    // stage A: 16 p x 32 chunks of 8 bf16, XOR-swizzled
#pragma unroll
    for (int it = 0; it < 2; ++it) {
      int c = tid + (it << 8);
      int pp = c >> 5, m = c & 31;
      short8v v = *(const short8v*)(tsh_b + pp * 2048 + ub + (m << 3));
      int dst = ((pp << 9) + (m << 4)) ^ ((pp & 7) << 4);
      *(short8v*)(smem + dst) = v;
    }
    // stage B replicas: 8 s x 48 chunks
    for (int c = tid; c < 384; c += 256) {
      int sr = c / 48;
      int m = c - sr * 48;
      short8v v = *(const short8v*)(grow + sr * 4104 + 8 + Q8 + (m << 3));
      *(short8v*)(smem + OFF_B + sr * REPB + (m << 4)) = v;
    }
    __syncthreads();
#pragma unroll 2
    for (int kc = 0; kc < 8; ++kc) {
      int ao = ((p16 << 9) + (kc << 6) + (g << 4)) ^ ((p16 & 7) << 4);
      short8v ahi = *(const short8v*)(smem + ao);
      int b0 = bB + (kc << 6);
      short8v bhi0 = *(const short8v*)(smem + b0);
      short8v bhi1 = *(const short8v*)(smem + b0 - 32);
      acc0 = __builtin_amdgcn_mfma_f32_16x16x32_bf16(ahi, bhi0, acc0, 0, 0, 0);
      acc1 = __builtin_amdgcn_mfma_f32_16x16x32_bf16(ahi, bhi1, acc1, 0, 0, 0);
    }
  }
  int t0c = tB + (w << 5) + p16;
#pragma unroll
  for (int rr = 0; rr < 4; ++rr) {
    int prow = (g << 2) + rr;
    expT[(size_t)(prow * 64 + j) * TL + t0c] = acc0[rr];
    expT[(size_t)(prow * 64 + j) * TL + t0c + 16] = acc1[rr];
  }
}

// ---------------------------------------------------------------------------
// env fused with mask: msk[p,j,t] = kerC[p][t+2046-j] - kerC[p][t]
// env[p,c,t] = sum_j E[c,j]*msk*exp(-K_c*expT[p,j,t])
// ---------------------------------------------------------------------------
__global__ __launch_bounds__(256) void env2_k(const float* __restrict__ energy,
                                              const float* __restrict__ props,
                                              const float* __restrict__ expT,
                                              const float* __restrict__ kerC,
                                              float* __restrict__ env) {
  int p = blockIdx.x >> 5, tile = blockIdx.x & 31;
  int tl = threadIdx.x & 63;
  int cg = threadIdx.x >> 6;
  int tC = tile * 64;
  int t = tC + tl;
  __shared__ float E[32][64];
  __shared__ float K[32];
  __shared__ float kcl[2112];
  for (int i = threadIdx.x; i < 2048; i += 256) E[i >> 6][i & 63] = energy[p * 2048 + i];
  const float* crow = kerC + p * 4096;
  for (int i = threadIdx.x; i < 2110; i += 256) kcl[i] = crow[tC + i];
  if (threadIdx.x < 32) {
    float mass = props[(p * 32 + threadIdx.x) * 2];
    float fric = props[(p * 32 + threadIdx.x) * 2 + 1];
    K[threadIdx.x] = fric / (2.0f * mass);
  }
  __syncthreads();
  float acc[8];
  float kk[8];
#pragma unroll
  for (int i = 0; i < 8; ++i) acc[i] = 0.f;
#pragma unroll
  for (int i = 0; i < 8; ++i) kk[i] = K[cg * 8 + i];
  float Ct = kcl[tl];
  const float* xrow = expT + (size_t)p * 64 * TL + t;
  for (int jj = 0; jj < 64; ++jj) {
    float x = xrow[jj * TL];
    float mv = kcl[tl + 2046 - jj] - Ct;
#pragma unroll
    for (int cc = 0; cc < 8; ++cc)
      acc[cc] = fmaf(E[cg * 8 + cc][jj] * mv, __expf(-kk[cc] * x), acc[cc]);
  }
#pragma unroll
  for (int cc = 0; cc < 8; ++cc)
    env[(size_t)(p * 32 + cg * 8 + cc) * TL + t] = acc[cc];
}

// ---------------------------------------------------------------------------
// Merged: blocks [0,512) = pos via MFMA (3-term hi/lo, unchanged math);
// blocks [512,528) = s-branch MLP.
// ---------------------------------------------------------------------------
__global__ __launch_bounds__(256) void pos_sbranch_k(const float* __restrict__ w_pos,
                                                     const float* __restrict__ b_pos,
                                                     float* __restrict__ pos,
                                                     const float* __restrict__ shape,
                                                     const float* __restrict__ w_layers,
                                                     const float* __restrict__ b_layers,
                                                     float* __restrict__ s64) {
  int bx = blockIdx.x;
  int tid = threadIdx.x;
  if (bx < 512) {
    int l = tid & 63, w = tid >> 6;
    int p16 = l & 15, g = l >> 4;
    int T0 = bx * 64 + w * 16;

    short8v bhi0[8], blo0[8], bhi1[8], blo1[8];
#pragma unroll
    for (int kc = 0; kc < 8; ++kc) {
#pragma unroll
      for (int ct = 0; ct < 2; ++ct) {
        const float* wrow = w_pos + (ct * 16 + p16) * 256 + kc * 32 + g * 8;
        float4v w0 = *(const float4v*)(wrow);
        float4v w1 = *(const float4v*)(wrow + 4);
        short8v hv, lv;
#pragma unroll
        for (int i = 0; i < 8; ++i) {
          float vv = (i < 4) ? w0[i] : w1[i - 4];
          unsigned short hb = bf16_rne(vv);
          float hf = __uint_as_float(((unsigned)hb) << 16);
          hv[i] = (short)hb;
          lv[i] = (short)bf16_rne(vv - hf);
        }
        if (ct == 0) { bhi0[kc] = hv; blo0[kc] = lv; }
        else         { bhi1[kc] = hv; blo1[kc] = lv; }
      }
    }

    float ttv = (float)(T0 + p16) * (32768.0f / 32767.0f);
    float4v acc0 = {0.f, 0.f, 0.f, 0.f};
    float4v acc1 = {0.f, 0.f, 0.f, 0.f};
#pragma unroll
    for (int kc = 0; kc < 8; ++kc) {
      short8v ahi, alo;
#pragma unroll
      for (int i = 0; i < 8; ++i) {
        int f = kc * 32 + g * 8 + i;
        float fr = 1e-5f + (float)f * ((0.5f - 1e-5f) / 255.0f);
        float rev = ttv * (0.5f * fr);
        float sv = __builtin_amdgcn_sinf(__builtin_amdgcn_fractf(rev));
        unsigned short hb = bf16_rne(sv);
        float hf = __uint_as_float(((unsigned)hb) << 16);
        ahi[i] = (short)hb;
        alo[i] = (short)bf16_rne(sv - hf);
      }
      acc0 = __builtin_amdgcn_mfma_f32_16x16x32_bf16(ahi, bhi0[kc], acc0, 0, 0, 0);
      acc1 = __builtin_amdgcn_mfma_f32_16x16x32_bf16(ahi, bhi1[kc], acc1, 0, 0, 0);
      acc0 = __builtin_amdgcn_mfma_f32_16x16x32_bf16(ahi, blo0[kc], acc0, 0, 0, 0);
      acc1 = __builtin_amdgcn_mfma_f32_16x16x32_bf16(ahi, blo1[kc], acc1, 0, 0, 0);
      acc0 = __builtin_amdgcn_mfma_f32_16x16x32_bf16(alo, bhi0[kc], acc0, 0, 0, 0);
      acc1 = __builtin_amdgcn_mfma_f32_16x16x32_bf16(alo, bhi1[kc], acc1, 0, 0, 0);
    }
    float bp0 = b_pos[p16], bp1 = b_pos[16 + p16];
    float4v o0, o1;
#pragma unroll
    for (int rr = 0; rr < 4; ++rr) {
      o0[rr] = acc0[rr] + bp0;
      o1[rr] = acc1[rr] + bp1;
    }
    int Tr = T0 + g * 4;
    *(float4v*)(pos + (size_t)p16 * 32768 + Tr) = o0;
    *(float4v*)(pos + (size_t)(16 + p16) * 32768 + Tr) = o1;
  } else {
    __shared__ float sA[64][33];
    __shared__ float sB[64][33];
    __shared__ float W[32][33];
    __shared__ float bb[32];
    int p = bx - 512;
    for (int idx = tid; idx < 2048; idx += 256) {
      int c = idx >> 6, f = idx & 63;
      sA[f][c] = shape[p * 2048 + idx];
    }
    int c = tid & 31, fg = tid >> 5;
    for (int ll = 0; ll < 4; ++ll) {
      for (int idx = tid; idx < 1024; idx += 256) W[idx >> 5][idx & 31] = w_layers[ll * 1024 + idx];
      if (tid < 32) bb[tid] = b_layers[ll * 32 + tid];
      __syncthreads();
      float(*cur)[33] = (ll & 1) ? sB : sA;
      float(*nxt)[33] = (ll & 1) ? sA : sB;
#pragma unroll
      for (int i = 0; i < 8; ++i) {
        int f = fg * 8 + i;
        float acc = cur[f][c] + bb[c];
#pragma unroll
        for (int k = 0; k < 32; ++k) acc = fmaf(fmaxf(cur[f][k], 0.f), W[c][k], acc);
        nxt[f][c] = acc;
      }
      __syncthreads();
    }
    for (int idx = tid; idx < 2048; idx += 256) {
      int cc = idx >> 6, f = idx & 63;
      s64[p * 2048 + idx] = fmaxf(sA[f][cc], 0.f);
    }
  }
}

// ---------------------------------------------------------------------------
// Final (unchanged)
// ---------------------------------------------------------------------------
__global__ __launch_bounds__(256) void final_k(const float* __restrict__ pos,
                                               const float* __restrict__ s64,
                                               const float* __restrict__ env,
                                               float* __restrict__ out) {
  int gid = blockIdx.x * 256 + threadIdx.x;
  int p = gid >> 15, T = gid & 32767;
  float ft = (float)T + 0.5f;
  float ce = fminf(fmaxf(ft * 0.0625f - 0.5f, 0.f), 2047.f);
  int ie = (int)ce;
  int ie1 = min(ie + 1, 2047);
  float we = ce - (float)ie;
  float cs = fminf(fmaxf(ft * (1.0f / 512.0f) - 0.5f, 0.f), 63.f);
  int is0 = (int)cs;
  int is1 = min(is0 + 1, 63);
  float ws = cs - (float)is0;
  const float* erow = env + (size_t)p * 32 * TL;
  const float* srow = s64 + p * 32 * 64;
  float acc = 0.f;
  for (int c = 0; c < 32; ++c) {
    float pv = pos[(size_t)c * 32768 + T];
    float ev = fmaxf(erow[c * TL + ie] * (1.f - we) + erow[c * TL + ie1] * we, 0.f);
    float sv = srow[c * 64 + is0] * (1.f - ws) + srow[c * 64 + is1] * ws;
    acc += pv * sv * ev;
  }
  out[gid] = acc;
}

extern "C" void kernel_launch(void* const* d_in, const int* in_sizes, int n_in,
                              void* d_out, int out_size, void* d_ws, size_t ws_size,
                              hipStream_t stream) {
  const float* time_in  = (const float*)d_in[0];
  const float* shifts   = (const float*)d_in[1];
  const float* energy   = (const float*)d_in[2];
  const float* shape    = (const float*)d_in[3];
  const float* props    = (const float*)d_in[4];
  const float* w_pos    = (const float*)d_in[5];
  const float* b_pos    = (const float*)d_in[6];
  const float* w_layers = (const float*)d_in[7];
  const float* b_layers = (const float*)d_in[8];

  float* ws = (float*)d_ws;
  float* kerE = ws;                                        // 65536 f
  float* kerC = ws + 65536;                                // 65536 f
  unsigned short* BFrep = (unsigned short*)(ws + 131072);  // 2101248 u16 = 1050624 f
  unsigned short* tsh_b = (unsigned short*)(ws + 1181696); // 32768 u16 = 16384 f
  float* expT = ws + 1198080;                              // 2097152 f
  float* env  = ws + 3295232;                              // 1048576 f
  float* pos  = ws + 4343808;                              // 1048576 f
  float* s64  = ws + 5392384;                              // 32768 f
  float* out  = (float*)d_out;

  hipLaunchKernelGGL(build_kernels_k, dim3(80), dim3(256), 0, stream, shifts, kerE, kerC, BFrep);
  hipLaunchKernelGGL(shift_time_k, dim3(128), dim3(256), 0, stream, time_in, kerE, tsh_b);
  hipLaunchKernelGGL(expT_mfma_k, dim3(1024), dim3(256), 0, stream, tsh_b, BFrep, expT);
  hipLaunchKernelGGL(env2_k, dim3(512), dim3(256), 0, stream, energy, props, expT, kerC, env);
  hipLaunchKernelGGL(pos_sbranch_k, dim3(528), dim3(256), 0, stream, w_pos, b_pos, pos,
                     shape, w_layers, b_layers, s64);
  hipLaunchKernelGGL(final_k, dim3(2048), dim3(256), 0, stream, pos, s64, env, out);
}